// Round 1
// baseline (1185.812 us; speedup 1.0000x reference)
//
#include <hip/hip_runtime.h>

#define PROMPT_LEN 2048
#define VOCAB 49408
#define DIM 768

// ws layout:
//   [0, VOCAB*4)        : c_sq (float per vocab row)
//   [VOCAB*4, VOCAB*8)  : candidate indices (int)
//   [VOCAB*8, +12)      : scalars: [0]=count, [1]=cmin bits, [2]=pmax_sq bits

__global__ void k_init(unsigned* scal) {
    if (threadIdx.x == 0) {
        scal[0] = 0u;            // candidate count
        scal[1] = 0x7F800000u;   // +inf  (min of c_sq, positive floats -> uint order)
        scal[2] = 0u;            // 0     (max of p_sq)
    }
}

// One wave per row; rows [0,VOCAB) are clip, [VOCAB, VOCAB+PROMPT_LEN) are prompt.
__global__ void __launch_bounds__(256) k_sumsq(const float* __restrict__ prompt,
                                               const float* __restrict__ clip,
                                               float* __restrict__ csq,
                                               unsigned* __restrict__ scal) {
    int wid  = threadIdx.x >> 6;
    int lane = threadIdx.x & 63;
    int row  = blockIdx.x * 4 + wid;
    bool is_clip = row < VOCAB;
    const float* src;
    if (is_clip) {
        src = clip + (size_t)row * DIM;
    } else {
        int pr = row - VOCAB;
        if (pr >= PROMPT_LEN) return;
        src = prompt + (size_t)pr * DIM;
    }
    float s = 0.f;
    #pragma unroll
    for (int i = 0; i < 3; ++i) {   // 768 floats = 3 * (64 lanes * float4)
        float4 v = ((const float4*)src)[i * 64 + lane];
        s += v.x * v.x + v.y * v.y + v.z * v.z + v.w * v.w;
    }
    #pragma unroll
    for (int m = 32; m >= 1; m >>= 1) s += __shfl_xor(s, m, 64);
    if (lane == 0) {
        if (is_clip) {
            csq[row] = s;
            atomicMin(&scal[1], __float_as_uint(s));
        } else {
            atomicMax(&scal[2], __float_as_uint(s));
        }
    }
}

// Keep v iff c_sq[v] - 2B*sqrt(c_sq[v]) <= min_u(c_sq[u] + 2B*sqrt(c_sq[u])).
// Monotone in c_sq (sqrt(c_sq) >> B), so threshold T solves T - 2B*sqrt(T) = U.
__global__ void k_compact(const float* __restrict__ csq, int* __restrict__ cand,
                          unsigned* __restrict__ scal) {
    float cmin    = __uint_as_float(scal[1]);
    float pmax_sq = __uint_as_float(scal[2]);
    float B  = sqrtf(pmax_sq) * 1.0001f + 1e-6f;
    float U  = cmin + 2.f * B * sqrtf(cmin) + 1.0f;   // +1.0 margin >> fp32 c_sq error
    float sT = B + sqrtf(B * B + U);
    float T  = sT * sT;
    int v = blockIdx.x * blockDim.x + threadIdx.x;
    if (v < VOCAB && csq[v] <= T) {
        int pos = atomicAdd((int*)&scal[0], 1);
        cand[pos] = v;
    }
}

// One wave per prompt row: exact fp64 ||p-c||^2 over candidates, lowest-index ties,
// fused gather epilogue out = (c - p) + p  (matches the reference's fp32 rounding).
__global__ void __launch_bounds__(256) k_refine(const float* __restrict__ prompt,
                                                const float* __restrict__ clip,
                                                const int* __restrict__ cand,
                                                const unsigned* __restrict__ scal,
                                                float* __restrict__ out) {
    int wid  = threadIdx.x >> 6;
    int lane = threadIdx.x & 63;
    int m = blockIdx.x * 4 + wid;
    if (m >= PROMPT_LEN) return;
    int count = (int)scal[0];

    const float* prow = prompt + (size_t)m * DIM;
    float  pf[12];
    double pd[12];
    #pragma unroll
    for (int i = 0; i < 3; ++i) {
        float4 v = ((const float4*)prow)[i * 64 + lane];
        pf[i*4+0] = v.x; pf[i*4+1] = v.y; pf[i*4+2] = v.z; pf[i*4+3] = v.w;
    }
    #pragma unroll
    for (int j = 0; j < 12; ++j) pd[j] = (double)pf[j];

    double best = 1e300;
    int bestIdx = 0x7fffffff;
    for (int ci = 0; ci < count; ++ci) {
        int v = cand[ci];
        const float* crow = clip + (size_t)v * DIM;
        double s = 0.0;
        #pragma unroll
        for (int i = 0; i < 3; ++i) {
            float4 c = ((const float4*)crow)[i * 64 + lane];
            double d0 = (double)c.x - pd[i*4+0];
            double d1 = (double)c.y - pd[i*4+1];
            double d2 = (double)c.z - pd[i*4+2];
            double d3 = (double)c.w - pd[i*4+3];
            s = fma(d0, d0, s); s = fma(d1, d1, s);
            s = fma(d2, d2, s); s = fma(d3, d3, s);
        }
        #pragma unroll
        for (int msk = 32; msk >= 1; msk >>= 1) s += __shfl_xor(s, msk, 64);
        if (s < best || (s == best && v < bestIdx)) { best = s; bestIdx = v; }
    }

    const float* crow = clip + (size_t)bestIdx * DIM;
    #pragma unroll
    for (int i = 0; i < 3; ++i) {
        float4 c = ((const float4*)crow)[i * 64 + lane];
        float4 o;
        o.x = (c.x - pf[i*4+0]) + pf[i*4+0];
        o.y = (c.y - pf[i*4+1]) + pf[i*4+1];
        o.z = (c.z - pf[i*4+2]) + pf[i*4+2];
        o.w = (c.w - pf[i*4+3]) + pf[i*4+3];
        ((float4*)(out + (size_t)m * DIM))[i * 64 + lane] = o;
    }
    if (lane == 0) out[(size_t)PROMPT_LEN * DIM + m] = (float)bestIdx;
}

extern "C" void kernel_launch(void* const* d_in, const int* in_sizes, int n_in,
                              void* d_out, int out_size, void* d_ws, size_t ws_size,
                              hipStream_t stream) {
    const float* prompt = (const float*)d_in[0];
    const float* clip   = (const float*)d_in[1];
    float* out = (float*)d_out;

    float*    csq  = (float*)d_ws;
    int*      cand = (int*)((char*)d_ws + (size_t)VOCAB * 4);
    unsigned* scal = (unsigned*)((char*)d_ws + (size_t)VOCAB * 8);

    k_init<<<1, 64, 0, stream>>>(scal);
    k_sumsq<<<(VOCAB + PROMPT_LEN) / 4, 256, 0, stream>>>(prompt, clip, csq, scal);
    k_compact<<<(VOCAB + 255) / 256, 256, 0, stream>>>(csq, cand, scal);
    k_refine<<<PROMPT_LEN / 4, 256, 0, stream>>>(prompt, clip, cand, scal, out);
}

// Round 2
// 470.263 us; speedup vs baseline: 2.5216x; 2.5216x over previous
//
#include <hip/hip_runtime.h>

#define PROMPT_LEN 2048
#define VOCAB 49408
#define DIM 768

// ws layout:
//   [0, VOCAB*4)                 : c_sq  (float per vocab row)
//   [VOCAB*4, VOCAB*8)           : candidate indices (int)
//   [VOCAB*8, VOCAB*8 + 2048*4)  : p_sq  (float per prompt row)
//   [... + 12]                   : scalars: [0]=count, [1]=cmin bits, [2]=pmax_sq bits

__global__ void k_init(unsigned* scal) {
    if (threadIdx.x == 0) {
        scal[0] = 0u;            // candidate count
        scal[1] = 0x7F800000u;   // +inf  (min of c_sq; positive floats -> uint order)
        scal[2] = 0u;            // 0     (max of p_sq)
    }
}

// One wave per row; rows [0,VOCAB) are clip, [VOCAB, VOCAB+PROMPT_LEN) are prompt.
// Pure streaming — NO single-address atomics (that was the 591us serialization).
__global__ void __launch_bounds__(256) k_sumsq(const float* __restrict__ prompt,
                                               const float* __restrict__ clip,
                                               float* __restrict__ csq,
                                               float* __restrict__ psq) {
    int wid  = threadIdx.x >> 6;
    int lane = threadIdx.x & 63;
    int row  = blockIdx.x * 4 + wid;
    bool is_clip = row < VOCAB;
    const float* src;
    int pr = row - VOCAB;
    if (is_clip) {
        src = clip + (size_t)row * DIM;
    } else {
        if (pr >= PROMPT_LEN) return;
        src = prompt + (size_t)pr * DIM;
    }
    float s = 0.f;
    #pragma unroll
    for (int i = 0; i < 3; ++i) {   // 768 floats = 3 * (64 lanes * float4)
        float4 v = ((const float4*)src)[i * 64 + lane];
        s += v.x * v.x + v.y * v.y + v.z * v.z + v.w * v.w;
    }
    #pragma unroll
    for (int m = 32; m >= 1; m >>= 1) s += __shfl_xor(s, m, 64);
    if (lane == 0) {
        if (is_clip) csq[row] = s;
        else         psq[pr]  = s;
    }
}

// Tiny reduction: cmin over csq, pmax over psq. 64 blocks -> 128 atomics total.
__global__ void __launch_bounds__(256) k_reduce(const float* __restrict__ csq,
                                                const float* __restrict__ psq,
                                                unsigned* __restrict__ scal) {
    int tid = blockIdx.x * 256 + threadIdx.x;
    const int stride = 64 * 256;
    float mn = 1e30f, mx = 0.f;
    for (int i = tid; i < VOCAB; i += stride)      mn = fminf(mn, csq[i]);
    for (int i = tid; i < PROMPT_LEN; i += stride) mx = fmaxf(mx, psq[i]);
    #pragma unroll
    for (int m = 32; m >= 1; m >>= 1) {
        mn = fminf(mn, __shfl_xor(mn, m, 64));
        mx = fmaxf(mx, __shfl_xor(mx, m, 64));
    }
    __shared__ float smn[4], smx[4];
    int wid = threadIdx.x >> 6, lane = threadIdx.x & 63;
    if (lane == 0) { smn[wid] = mn; smx[wid] = mx; }
    __syncthreads();
    if (threadIdx.x == 0) {
        mn = fminf(fminf(smn[0], smn[1]), fminf(smn[2], smn[3]));
        mx = fmaxf(fmaxf(smx[0], smx[1]), fmaxf(smx[2], smx[3]));
        atomicMin(&scal[1], __float_as_uint(mn));
        atomicMax(&scal[2], __float_as_uint(mx));
    }
}

// Keep v iff c_sq[v] - 2B*sqrt(c_sq[v]) <= min_u (c_sq[u] + 2B*sqrt(c_sq[u])).
// Monotone in c_sq, so threshold T solves T - 2B*sqrt(T) = U. Exact pruning.
__global__ void k_compact(const float* __restrict__ csq, int* __restrict__ cand,
                          unsigned* __restrict__ scal) {
    float cmin    = __uint_as_float(scal[1]);
    float pmax_sq = __uint_as_float(scal[2]);
    float B  = sqrtf(pmax_sq) * 1.0001f + 1e-6f;
    float U  = cmin + 2.f * B * sqrtf(cmin) + 1.0f;   // +1.0 margin >> fp32 c_sq error
    float sT = B + sqrtf(B * B + U);
    float T  = sT * sT;
    int v = blockIdx.x * blockDim.x + threadIdx.x;
    if (v < VOCAB && csq[v] <= T) {
        int pos = atomicAdd((int*)&scal[0], 1);
        cand[pos] = v;
    }
}

// One BLOCK (4 waves) per prompt row; candidates strided across waves.
// Exact fp64 ||p-c||^2, lowest-index tie-break, fused gather epilogue.
__global__ void __launch_bounds__(256) k_refine(const float* __restrict__ prompt,
                                                const float* __restrict__ clip,
                                                const int* __restrict__ cand,
                                                const unsigned* __restrict__ scal,
                                                float* __restrict__ out) {
    int wid  = threadIdx.x >> 6;
    int lane = threadIdx.x & 63;
    int m = blockIdx.x;
    int count = (int)scal[0];

    const float* prow = prompt + (size_t)m * DIM;
    double pd[12];
    #pragma unroll
    for (int i = 0; i < 3; ++i) {
        float4 v = ((const float4*)prow)[i * 64 + lane];
        pd[i*4+0] = (double)v.x; pd[i*4+1] = (double)v.y;
        pd[i*4+2] = (double)v.z; pd[i*4+3] = (double)v.w;
    }

    double best = 1e300;
    int bestIdx = 0x7fffffff;
    for (int ci = wid; ci < count; ci += 4) {
        int v = cand[ci];
        const float* crow = clip + (size_t)v * DIM;
        double s = 0.0;
        #pragma unroll
        for (int i = 0; i < 3; ++i) {
            float4 c = ((const float4*)crow)[i * 64 + lane];
            double d0 = (double)c.x - pd[i*4+0];
            double d1 = (double)c.y - pd[i*4+1];
            double d2 = (double)c.z - pd[i*4+2];
            double d3 = (double)c.w - pd[i*4+3];
            s = fma(d0, d0, s); s = fma(d1, d1, s);
            s = fma(d2, d2, s); s = fma(d3, d3, s);
        }
        #pragma unroll
        for (int msk = 32; msk >= 1; msk >>= 1) s += __shfl_xor(s, msk, 64);
        if (s < best || (s == best && v < bestIdx)) { best = s; bestIdx = v; }
    }

    __shared__ double sBest[4];
    __shared__ int    sIdx[4];
    if (lane == 0) { sBest[wid] = best; sIdx[wid] = bestIdx; }
    __syncthreads();
    if (threadIdx.x == 0) {
        double b = sBest[0]; int bi = sIdx[0];
        #pragma unroll
        for (int w = 1; w < 4; ++w) {
            if (sBest[w] < b || (sBest[w] == b && sIdx[w] < bi)) { b = sBest[w]; bi = sIdx[w]; }
        }
        sIdx[0] = bi;
    }
    __syncthreads();
    int win = sIdx[0];

    // epilogue: 192 float4s across the block; out = (c - p) + p in fp32
    if (threadIdx.x < 192) {
        float4 c = ((const float4*)(clip + (size_t)win * DIM))[threadIdx.x];
        float4 p = ((const float4*)prow)[threadIdx.x];
        float4 o;
        o.x = (c.x - p.x) + p.x;
        o.y = (c.y - p.y) + p.y;
        o.z = (c.z - p.z) + p.z;
        o.w = (c.w - p.w) + p.w;
        ((float4*)(out + (size_t)m * DIM))[threadIdx.x] = o;
    }
    if (threadIdx.x == 0) out[(size_t)PROMPT_LEN * DIM + m] = (float)win;
}

extern "C" void kernel_launch(void* const* d_in, const int* in_sizes, int n_in,
                              void* d_out, int out_size, void* d_ws, size_t ws_size,
                              hipStream_t stream) {
    const float* prompt = (const float*)d_in[0];
    const float* clip   = (const float*)d_in[1];
    float* out = (float*)d_out;

    float*    csq  = (float*)d_ws;
    int*      cand = (int*)((char*)d_ws + (size_t)VOCAB * 4);
    float*    psq  = (float*)((char*)d_ws + (size_t)VOCAB * 8);
    unsigned* scal = (unsigned*)((char*)d_ws + (size_t)VOCAB * 8 + (size_t)PROMPT_LEN * 4);

    k_init<<<1, 64, 0, stream>>>(scal);
    k_sumsq<<<(VOCAB + PROMPT_LEN) / 4, 256, 0, stream>>>(prompt, clip, csq, psq);
    k_reduce<<<64, 256, 0, stream>>>(csq, psq, scal);
    k_compact<<<(VOCAB + 255) / 256, 256, 0, stream>>>(csq, cand, scal);
    k_refine<<<PROMPT_LEN, 256, 0, stream>>>(prompt, clip, cand, scal, out);
}